// Round 5
// baseline (495.573 us; speedup 1.0000x reference)
//
#include <hip/hip_runtime.h>
#include <hip/hip_fp16.h>
#include <math.h>
#include <stdint.h>

#define D_DIM    512
#define NCLS     1000
#define KSEL     200
#define NBINS    1024         // bin width 2.0, covers d2 in [0, 2048)
#define HREP     4            // replicated LDS histograms (atomic contention)
#define CAND_MAX 2048
#define GCONST   0.005        // 1/(2*sigma^2), sigma=10
#define MARGIN   4.0f         // covers f16-d2 ulp (0.5) + bf16 GEMM error + bin edge

typedef short s8v __attribute__((ext_vector_type(8)));
typedef float f4v __attribute__((ext_vector_type(4)));

// RTNE f32 -> bf16 (inputs finite)
static __device__ __forceinline__ unsigned short f2bf(float x) {
    unsigned u = __float_as_uint(x);
    return (unsigned short)((u + 0x7FFFu + ((u >> 16) & 1u)) >> 16);
}

// packed RTNE f32x2 -> bf16x2, single instruction (no builtin on gfx950)
static __device__ __forceinline__ unsigned cvt_pk_bf16(float lo, float hi) {
    unsigned r;
    asm("v_cvt_pk_bf16_f32 %0, %1, %2" : "=v"(r) : "v"(lo), "v"(hi));
    return r;
}

// ------------------------------------------------- convert F (+ row norms)
__global__ __launch_bounds__(256)
void convertF(const float* __restrict__ F, unsigned short* __restrict__ Fb,
              float* __restrict__ f2)
{
    __shared__ float red[256];
    const int r = blockIdx.x, t = threadIdx.x;
    float2 v = *(const float2*)(F + (size_t)r * D_DIM + t * 2);
    ushort2 o; o.x = f2bf(v.x); o.y = f2bf(v.y);
    *(ushort2*)(Fb + (size_t)r * D_DIM + t * 2) = o;
    red[t] = v.x * v.x + v.y * v.y;
    __syncthreads();
    for (int off = 128; off > 0; off >>= 1) {
        if (t < off) red[t] += red[t + off];
        __syncthreads();
    }
    if (t == 0) f2[r] = red[0];
}

// ------------------------------------------------- FUSED MFMA GEMM, BM=256
// 512 threads = 8 waves (4m x 2n). No global_load_lds anywhere:
//  * A fragments loaded straight from global Fb (512 KB, L2-resident) per
//    MFMA phase — per-lane addr matches the MFMA A-operand layout exactly.
//  * B read as f32 from C (reg prefetch for k+1 in flight across barriers —
//    T14: reg-destination loads aren't drained by __syncthreads), converted
//    bf16 in-register (v_cvt_pk_bf16_f32), staged to DOUBLE-BUFFERED Bs with
//    octet-XOR swizzle; c2 row norms accumulated on the fly.
// => ONE barrier per K-step (8 total), whose only wait is lgkmcnt on the
//    just-completed Bs writes. No vmcnt(0) drain anywhere in the loop.
// Grid m-fastest: 2 m-blocks of an n-stripe co-run, C f32 HBM-fetched ~once
// (r4 FETCH=206MB evidence). Epilogue: d2 = f2[m]+c2[n]-2*S, stored f16.
__global__ __launch_bounds__(512)
void mfma_gemm(const unsigned short* __restrict__ Fb,
               const float* __restrict__ C,
               const float* __restrict__ f2,
               __half* __restrict__ Dm, int N)
{
    __shared__ short smem[2 * 128 * 64];   // Bs dbuf 2x16KB; reused as Cs 32KB
    __shared__ float c2s[128];
    const int t    = threadIdx.x;
    const int lane = t & 63;
    const int w    = t >> 6;             // wave 0..7
    const int wm   = w >> 1, wn = w & 1; // wm 0..3 (64 rows), wn 0..1 (64 cols)
    const int m0   = blockIdx.x * 256;   // m fastest
    const int n0   = blockIdx.y * 128;
    const int lrow = lane >> 3;          // 0..7 within staging chunk
    const int oct  = (lane & 7) ^ lrow;  // swizzled global k octet (B staging)
    const int quad = lane >> 4;          // 0..3
    const int col  = lane & 15;

    f4v acc[4][4];
#pragma unroll
    for (int i = 0; i < 4; ++i)
#pragma unroll
        for (int j = 0; j < 4; ++j) acc[i][j] = (f4v){0.f, 0.f, 0.f, 0.f};

    float  c2part[2] = {0.f, 0.f};
    float4 ra[2], rb[2];

    // per-i A row base (global): row = m0 + wm*64 + i*16 + col, k-off quad*8
    const unsigned short* Arow[4];
#pragma unroll
    for (int i = 0; i < 4; ++i)
        Arow[i] = Fb + (size_t)(m0 + wm * 64 + i * 16 + col) * D_DIM + quad * 8;

    // preload B f32 for k0 = 0 (2 chunks/wave: 16 chunks = 128 rows)
#pragma unroll
    for (int cc = 0; cc < 2; ++cc) {
        int row = (w * 2 + cc) * 8 + lrow;
        int rg  = n0 + row; rg = rg < N ? rg : N - 1;   // clamp tail
        const float* gp = C + (size_t)rg * D_DIM + oct * 8;
        ra[cc] = *(const float4*)gp;
        rb[cc] = *(const float4*)(gp + 4);
    }

    int buf = 0;
    for (int k0 = 0; k0 < D_DIM; k0 += 64, buf ^= 1) {
        short* Bs = smem + buf * (128 * 64);
        // convert + stage B(k0) into Bs[buf]; accumulate c2
#pragma unroll
        for (int cc = 0; cc < 2; ++cc) {
            int row = (w * 2 + cc) * 8 + lrow;
            float4 va = ra[cc], vb = rb[cc];
            c2part[cc] += va.x*va.x + va.y*va.y + va.z*va.z + va.w*va.w
                        + vb.x*vb.x + vb.y*vb.y + vb.z*vb.z + vb.w*vb.w;
            uint4 o;
            o.x = cvt_pk_bf16(va.x, va.y);
            o.y = cvt_pk_bf16(va.z, va.w);
            o.z = cvt_pk_bf16(vb.x, vb.y);
            o.w = cvt_pk_bf16(vb.z, vb.w);
            // LDS slot (lane&7) holds global octet (lane&7)^lrow == oct
            *(uint4*)&Bs[row * 64 + (lane & 7) * 8] = o;
        }
        // prefetch next B f32 — stays in flight across the barrier (T14)
        if (k0 + 64 < D_DIM) {
#pragma unroll
            for (int cc = 0; cc < 2; ++cc) {
                int row = (w * 2 + cc) * 8 + lrow;
                int rg  = n0 + row; rg = rg < N ? rg : N - 1;
                const float* gp = C + (size_t)rg * D_DIM + (k0 + 64) + oct * 8;
                ra[cc] = *(const float4*)gp;
                rb[cc] = *(const float4*)(gp + 4);
            }
        }
        __syncthreads();   // Bs[buf] visible; dbuf gives one-step write slack

        // MFMA phase: B from LDS (swizzled), A straight from global (L2-hot)
#pragma unroll
        for (int kk = 0; kk < 2; ++kk) {
            int slot = (kk * 4 + quad) ^ (col & 7);
            s8v b[4];
#pragma unroll
            for (int j = 0; j < 4; ++j) {
                int row = wn * 64 + j * 16 + col;
                b[j] = *(s8v*)&Bs[row * 64 + slot * 8];
            }
            s8v a[4];
#pragma unroll
            for (int i = 0; i < 4; ++i)
                a[i] = *(const s8v*)(Arow[i] + k0 + kk * 32);
#pragma unroll
            for (int i = 0; i < 4; ++i)
#pragma unroll
                for (int j = 0; j < 4; ++j)
                    acc[i][j] = __builtin_amdgcn_mfma_f32_16x16x32_bf16(
                        a[i], b[j], acc[i][j], 0, 0, 0);
        }
    }

    // ---- c2 row norms -> LDS (reduce over the 8 lanes sharing each row)
#pragma unroll
    for (int cc = 0; cc < 2; ++cc) {
        float s = c2part[cc];
        s += __shfl_xor(s, 1, 64);
        s += __shfl_xor(s, 2, 64);
        s += __shfl_xor(s, 4, 64);
        int row = (w * 2 + cc) * 8 + lrow;
        if ((lane & 7) == 0) c2s[row] = s;
    }
    __syncthreads();                 // c2s visible; all MFMA LDS reads done

    // ---- epilogue: d2 = f2[m] + c2[n] - 2*S, pack f16 (octet-swizzled), store
    float c2v[4];
#pragma unroll
    for (int j = 0; j < 4; ++j)
        c2v[j] = c2s[wn * 64 + j * 16 + col];
    float fv[4][4];
#pragma unroll
    for (int i = 0; i < 4; ++i)
#pragma unroll
        for (int v = 0; v < 4; ++v)
            fv[i][v] = f2[m0 + wm * 64 + i * 16 + quad * 4 + v];

    __half* Cs = (__half*)smem;      // 128 x 128 f16 = 32 KB (half tile)
#pragma unroll
    for (int h = 0; h < 2; ++h) {
        __syncthreads();             // smem free (h=0) / prev half stored (h=1)
        if ((wm >> 1) == h) {
            int mlb = (wm & 1) * 64;
#pragma unroll
            for (int i = 0; i < 4; ++i) {
#pragma unroll
                for (int j = 0; j < 4; ++j) {
#pragma unroll
                    for (int v = 0; v < 4; ++v) {
                        int ml = mlb + i * 16 + quad * 4 + v;   // 0..127
                        int nl = wn * 64 + j * 16 + col;        // 0..127
                        float d2 = fv[i][v] + c2v[j] - 2.f * acc[i][j][v];
                        int slot = (nl >> 3) ^ (ml & 7);
                        Cs[ml * 128 + slot * 8 + (nl & 7)] = __float2half(d2);
                    }
                }
            }
        }
        __syncthreads();
#pragma unroll
        for (int it = 0; it < 4; ++it) {
            int idx = it * 512 + t;  // 0..2047
            int row = idx >> 4;      // 0..127
            int o8  = idx & 15;
            int n   = n0 + o8 * 8;
            const __half* src = &Cs[row * 128 + ((o8 ^ (row & 7)) * 8)];
            __half* dst = Dm + (size_t)(m0 + h * 128 + row) * N + n;
            if (n + 7 < N) {
                *(uint4*)dst = *(const uint4*)src;
            } else if (n < N) {
                for (int e = 0; e < 8 && n + e < N; ++e) dst[e] = src[e];
            }
        }
    }
}

// ------------------------------------------------- fused per-row (1024 thr):
// Dm holds f16 d2 directly. hist -> threshold -> collect -> exact f64 top-K
// -> class scatter -> log.
__global__ __launch_bounds__(1024)
void fused_select(const __half* __restrict__ Dm,
                  const float* __restrict__ F, const float* __restrict__ C,
                  const int* __restrict__ labels, const float* __restrict__ weight,
                  float* __restrict__ out, int N)
{
    __shared__ unsigned hist[NBINS * HREP]; // 16 KB, 4 replicated copies
    __shared__ float    fs[D_DIM];
    __shared__ int      idxs[CAND_MAX];
    __shared__ double   dists[CAND_MAX];
    __shared__ float    p[NCLS];
    __shared__ float    red[1024];
    __shared__ unsigned scanbuf[256];
    __shared__ float    sT;
    __shared__ unsigned scnt;

    const int r = blockIdx.x, t = threadIdx.x;
    for (int b = t; b < NBINS * HREP; b += 1024) hist[b] = 0u;
    for (int c = t; c < NCLS; c += 1024) p[c] = 0.f;
    for (int k = t; k < D_DIM; k += 1024) fs[k] = F[(size_t)r * D_DIM + k];
    if (t == 0) { sT = 1e30f; scnt = 0u; }
    __syncthreads();

    const __half* srow = Dm + (size_t)r * N;

    // ---- pass 1: histogram, 8 elems/thread/iter (N % 8 == 0)
    for (int j = t * 8; j < N; j += 8192) {
        uint4 sv = *(const uint4*)(srow + j);
        float2 s0 = __half22float2(*(__half2*)&sv.x);
        float2 s1 = __half22float2(*(__half2*)&sv.y);
        float2 s2 = __half22float2(*(__half2*)&sv.z);
        float2 s3 = __half22float2(*(__half2*)&sv.w);
        float d2v[8] = { s0.x, s0.y, s1.x, s1.y, s2.x, s2.y, s3.x, s3.y };
#pragma unroll
        for (int e = 0; e < 8; ++e) {
            int b = (int)(d2v[e] * 0.5f);
            b = b < 0 ? 0 : (b > NBINS - 1 ? NBINS - 1 : b);
            atomicAdd(&hist[(b << 2) + (t & 3)], 1u);
        }
    }
    __syncthreads();

    // ---- threshold: blocked cumulative scan on first 256 threads
    if (t < 256) {
        unsigned loc[NBINS / 256];
        unsigned s = 0;
#pragma unroll
        for (int i = 0; i < NBINS / 256; ++i) {
            int bb = t * (NBINS / 256) + i;
            loc[i] = hist[(bb << 2) + 0] + hist[(bb << 2) + 1]
                   + hist[(bb << 2) + 2] + hist[(bb << 2) + 3];
            s += loc[i];
        }
        scanbuf[t] = s;
        __syncthreads();
        unsigned pre = 0;
        for (int u = 0; u < t; ++u) pre += scanbuf[u];
        if (pre < KSEL && pre + s >= KSEL) {
            unsigned cum = pre;
            int b = NBINS - 1;
#pragma unroll
            for (int i = 0; i < NBINS / 256; ++i) {
                cum += loc[i];
                if (cum >= KSEL) { b = t * (NBINS / 256) + i; break; }
            }
            sT = 2.0f * (float)(b + 1) + MARGIN;
        }
    } else {
        __syncthreads();
    }
    __syncthreads();
    const float Tr = sT;

    // ---- pass 2: collect candidate indices (row LLC-hot)
    for (int j = t * 8; j < N; j += 8192) {
        uint4 sv = *(const uint4*)(srow + j);
        float2 s0 = __half22float2(*(__half2*)&sv.x);
        float2 s1 = __half22float2(*(__half2*)&sv.y);
        float2 s2 = __half22float2(*(__half2*)&sv.z);
        float2 s3 = __half22float2(*(__half2*)&sv.w);
        float d2v[8] = { s0.x, s0.y, s1.x, s1.y, s2.x, s2.y, s3.x, s3.y };
#pragma unroll
        for (int e = 0; e < 8; ++e) {
            if (d2v[e] <= Tr) {
                unsigned pos = atomicAdd(&scnt, 1u);
                if (pos < CAND_MAX) idxs[pos] = j + e;
            }
        }
    }
    __syncthreads();
    int Nc = (int)scnt;
    if (Nc > CAND_MAX) Nc = CAND_MAX;

    // ---- exact f64 distances: one WAVE per candidate, coalesced C gather
    {
        const int wv = t >> 6, lane = t & 63;
        for (int i = wv; i < Nc; i += 16) {
            int ci = idxs[i];
            const float* cp = C + (size_t)ci * D_DIM;
            float4 a  = *(const float4*)(cp + lane * 8);
            float4 b  = *(const float4*)(cp + lane * 8 + 4);
            float4 fa = *(const float4*)(fs + lane * 8);
            float4 fb = *(const float4*)(fs + lane * 8 + 4);
            double d0 = (double)fa.x - (double)a.x;
            double d1 = (double)fa.y - (double)a.y;
            double d2 = (double)fa.z - (double)a.z;
            double d3 = (double)fa.w - (double)a.w;
            double d4 = (double)fb.x - (double)b.x;
            double d5 = (double)fb.y - (double)b.y;
            double d6 = (double)fb.z - (double)b.z;
            double d7 = (double)fb.w - (double)b.w;
            double acc = d0*d0 + d1*d1 + d2*d2 + d3*d3
                       + d4*d4 + d5*d5 + d6*d6 + d7*d7;
#pragma unroll
            for (int off = 32; off > 0; off >>= 1)
                acc += __shfl_down(acc, off, 64);
            if (lane == 0) dists[i] = acc;
        }
    }
    __syncthreads();

    // ---- exact rank-based top-KSEL (tie-break: lower index, lax.top_k order)
    int ksel = KSEL < Nc ? KSEL : Nc;
    for (int i = t; i < Nc; i += 1024) {
        double di = dists[i];
        int    ii = idxs[i];
        int rank = 0;
        for (int j = 0; j < Nc; ++j) {
            double dj = dists[j];
            rank += (dj < di) || (dj == di && idxs[j] < ii);
        }
        if (rank < ksel) {
            double wgt = exp(-di * GCONST) * exp((double)weight[ii]);
            atomicAdd(&p[labels[ii]], (float)wgt);
        }
    }
    __syncthreads();

    // ---- p==0 -> 1e-10, normalize, log
    float s = 0.f;
    for (int c = t; c < NCLS; c += 1024) {
        float v = p[c];
        if (v == 0.f) v = 1e-10f;
        p[c] = v;
        s += v;
    }
    red[t] = s;
    __syncthreads();
    for (int o = 512; o > 0; o >>= 1) {
        if (t < o) red[t] += red[t + o];
        __syncthreads();
    }
    float total = red[0];
    for (int c = t; c < NCLS; c += 1024)
        out[(size_t)r * NCLS + c] = logf(p[c] / total);
}

// ------------------------------------------------- launch
extern "C" void kernel_launch(void* const* d_in, const int* in_sizes, int n_in,
                              void* d_out, int out_size, void* d_ws, size_t ws_size,
                              hipStream_t stream)
{
    const float* features = (const float*)d_in[0];
    const float* centres  = (const float*)d_in[1];
    const int*   labels   = (const int*)d_in[2];
    const float* weight   = (const float*)d_in[3];
    const int B = in_sizes[0] / D_DIM;   // 512
    const int N = in_sizes[2];           // 100000
    float* out = (float*)d_out;

    uint8_t* w = (uint8_t*)d_ws;
    size_t off = 0;
    auto alloc = [&](size_t bytes) -> uint8_t* {
        uint8_t* ptr = w + off;
        off = (off + bytes + 255) & ~(size_t)255;
        return ptr;
    };
    float*          f2 = (float*)alloc((size_t)B * 4);
    unsigned short* Fb = (unsigned short*)alloc((size_t)B * D_DIM * 2);
    __half*         Dm = (__half*)alloc((size_t)B * N * 2);
    (void)ws_size;

    convertF<<<B, 256, 0, stream>>>(features, Fb, f2);

    dim3 ggrid(B / 256, (N + 127) / 128);   // m fastest
    mfma_gemm<<<ggrid, 512, 0, stream>>>(Fb, centres, f2, Dm, N);

    fused_select<<<B, 1024, 0, stream>>>(Dm, features, centres,
                                         labels, weight, out, N);
}

// Round 6
// 444.250 us; speedup vs baseline: 1.1155x; 1.1155x over previous
//
#include <hip/hip_runtime.h>
#include <hip/hip_fp16.h>
#include <math.h>
#include <stdint.h>

#define D_DIM    512
#define NCLS     1000
#define KSEL     200
#define NBINS    1024         // bin width 2.0, covers d2 in [0, 2048)
#define HREP     4            // replicated LDS histograms (atomic contention)
#define CAND_MAX 2048
#define GCONST   0.005        // 1/(2*sigma^2), sigma=10
#define MARGIN   4.0f         // covers f16-d2 ulp (0.5) + bf16 GEMM error + bin edge

typedef short s8v __attribute__((ext_vector_type(8)));
typedef float f4v __attribute__((ext_vector_type(4)));

#define GLOAD_LDS16(gp, lp) __builtin_amdgcn_global_load_lds( \
    (const __attribute__((address_space(1))) void*)(gp),      \
    (__attribute__((address_space(3))) void*)(lp), 16, 0, 0)

// RTNE f32 -> bf16 (inputs finite)
static __device__ __forceinline__ unsigned short f2bf(float x) {
    unsigned u = __float_as_uint(x);
    return (unsigned short)((u + 0x7FFFu + ((u >> 16) & 1u)) >> 16);
}

// packed RTNE f32x2 -> bf16x2, single instruction (no builtin on gfx950)
static __device__ __forceinline__ unsigned cvt_pk_bf16(float lo, float hi) {
    unsigned r;
    asm("v_cvt_pk_bf16_f32 %0, %1, %2" : "=v"(r) : "v"(lo), "v"(hi));
    return r;
}

// ------------------------------------------------- convert F (+ row norms)
__global__ __launch_bounds__(256)
void convertF(const float* __restrict__ F, unsigned short* __restrict__ Fb,
              float* __restrict__ f2)
{
    __shared__ float red[256];
    const int r = blockIdx.x, t = threadIdx.x;
    float2 v = *(const float2*)(F + (size_t)r * D_DIM + t * 2);
    ushort2 o; o.x = f2bf(v.x); o.y = f2bf(v.y);
    *(ushort2*)(Fb + (size_t)r * D_DIM + t * 2) = o;
    red[t] = v.x * v.x + v.y * v.y;
    __syncthreads();
    for (int off = 128; off > 0; off >>= 1) {
        if (t < off) red[t] += red[t + off];
        __syncthreads();
    }
    if (t == 0) f2[r] = red[0];
}

// ------------------------------------------------- FUSED MFMA GEMM, BM=256
// 512 threads = 8 waves (4m x 2n), counted-vmcnt pipeline (T3/T4):
//  * As DOUBLE-buffered (2x32KB), staged via global_load_lds w=16 from bf16
//    Fb (octet-XOR pre-swizzled global source, LDS dest linear). Iter k
//    issues A(k+1) into As[buf^1], then waits vmcnt(8): retires ONLY the 4
//    oldest VMEM ops = A(k)'s staging. B-reg(k+1) and A(k+1) stay in flight
//    across the RAW barrier (no vmcnt(0) drain anywhere in the loop).
//  * Bs single buffer: B read as f32 (reg prefetch), converted bf16
//    in-register (v_cvt_pk_bf16_f32), ds_written at iter top (safe: after
//    the post-MFMA barrier of iter k-1); c2 row norms on the fly.
//  * Raw s_barrier x2 per K-step; compiler handles B-reg waits (precise).
// Grid m-fastest: 2 m-blocks of an n-stripe co-run, C f32 HBM-fetched ~once
// (r4 FETCH=206MB evidence). Epilogue: d2 = f2[m]+c2[n]-2*S, stored f16.
__global__ __launch_bounds__(512)
void mfma_gemm(const unsigned short* __restrict__ Fb,
               const float* __restrict__ C,
               const float* __restrict__ f2,
               __half* __restrict__ Dm, int N)
{
    __shared__ short smem[2 * 256 * 64 + 128 * 64]; // As dbuf 64KB | Bs 16KB
    short* BsBase = smem + 2 * 256 * 64;
    const int t    = threadIdx.x;
    const int lane = t & 63;
    const int w    = t >> 6;             // wave 0..7
    const int wm   = w >> 1, wn = w & 1; // wm 0..3 (64 rows), wn 0..1 (64 cols)
    const int m0   = blockIdx.x * 256;   // m fastest
    const int n0   = blockIdx.y * 128;
    const int lrow = lane >> 3;          // 0..7 within staging chunk
    const int oct  = (lane & 7) ^ lrow;  // swizzled global k octet
    const int quad = lane >> 4;          // 0..3
    const int col  = lane & 15;

    f4v acc[4][4];
#pragma unroll
    for (int i = 0; i < 4; ++i)
#pragma unroll
        for (int j = 0; j < 4; ++j) acc[i][j] = (f4v){0.f, 0.f, 0.f, 0.f};

    float  c2part[2] = {0.f, 0.f};
    float4 ra[2], rb[2];

    // prologue: issue B-reg(0), then A(0) -> As[0]
#pragma unroll
    for (int cc = 0; cc < 2; ++cc) {
        int row = (w * 2 + cc) * 8 + lrow;
        int rg  = n0 + row; rg = rg < N ? rg : N - 1;   // clamp tail
        const float* gp = C + (size_t)rg * D_DIM + oct * 8;
        ra[cc] = *(const float4*)gp;
        rb[cc] = *(const float4*)(gp + 4);
    }
#pragma unroll
    for (int cc = 0; cc < 4; ++cc) {
        int ch = w * 4 + cc;     // A chunks 0..31 (8 rows each, 256 rows)
        GLOAD_LDS16(Fb + (size_t)(m0 + ch * 8 + lrow) * D_DIM + 0 + oct * 8,
                    &smem[ch * 512]);
    }

    int buf = 0;
    for (int k0 = 0; k0 < D_DIM; k0 += 64, buf ^= 1) {
        short* As  = smem + buf * (256 * 64);
        short* Asn = smem + (buf ^ 1) * (256 * 64);
        short* Bs  = BsBase;

        // convert + stage B(k0) into Bs; accumulate c2
        // (compiler inserts a precise vmcnt wait for ra/rb here)
#pragma unroll
        for (int cc = 0; cc < 2; ++cc) {
            int row = (w * 2 + cc) * 8 + lrow;
            float4 va = ra[cc], vb = rb[cc];
            c2part[cc] += va.x*va.x + va.y*va.y + va.z*va.z + va.w*va.w
                        + vb.x*vb.x + vb.y*vb.y + vb.z*vb.z + vb.w*vb.w;
            uint4 o;
            o.x = cvt_pk_bf16(va.x, va.y);
            o.y = cvt_pk_bf16(va.z, va.w);
            o.z = cvt_pk_bf16(vb.x, vb.y);
            o.w = cvt_pk_bf16(vb.z, vb.w);
            // LDS slot (lane&7) holds global octet (lane&7)^lrow == oct
            *(uint4*)&Bs[row * 64 + (lane & 7) * 8] = o;
        }

        if (k0 + 64 < D_DIM) {
            // issue B-reg(k+1) — stays in flight across the barrier
#pragma unroll
            for (int cc = 0; cc < 2; ++cc) {
                int row = (w * 2 + cc) * 8 + lrow;
                int rg  = n0 + row; rg = rg < N ? rg : N - 1;
                const float* gp = C + (size_t)rg * D_DIM + (k0 + 64) + oct * 8;
                ra[cc] = *(const float4*)gp;
                rb[cc] = *(const float4*)(gp + 4);
            }
            // issue A-stage(k+1) -> As[buf^1] — also stays in flight
#pragma unroll
            for (int cc = 0; cc < 4; ++cc) {
                int ch = w * 4 + cc;
                GLOAD_LDS16(Fb + (size_t)(m0 + ch * 8 + lrow) * D_DIM
                                + (k0 + 64) + oct * 8,
                            &Asn[ch * 512]);
            }
            // retire ONLY the 4 oldest VMEM ops = A(k0) staging; keep 8 in flight
            asm volatile("s_waitcnt vmcnt(8) lgkmcnt(0)" ::: "memory");
        } else {
            asm volatile("s_waitcnt vmcnt(0) lgkmcnt(0)" ::: "memory");
        }
        __builtin_amdgcn_s_barrier();   // raw: no implicit vmcnt(0) drain
        asm volatile("" ::: "memory");

        // MFMA phase: A and B fragments from LDS (octet-XOR slots)
#pragma unroll
        for (int kk = 0; kk < 2; ++kk) {
            int slot = (kk * 4 + quad) ^ (col & 7);
            s8v b[4];
#pragma unroll
            for (int j = 0; j < 4; ++j) {
                int row = wn * 64 + j * 16 + col;
                b[j] = *(s8v*)&Bs[row * 64 + slot * 8];
            }
            s8v a[4];
#pragma unroll
            for (int i = 0; i < 4; ++i) {
                int row = wm * 64 + i * 16 + col;
                a[i] = *(s8v*)&As[row * 64 + slot * 8];
            }
#pragma unroll
            for (int i = 0; i < 4; ++i)
#pragma unroll
                for (int j = 0; j < 4; ++j)
                    acc[i][j] = __builtin_amdgcn_mfma_f32_16x16x32_bf16(
                        a[i], b[j], acc[i][j], 0, 0, 0);
        }
        __builtin_amdgcn_s_barrier();   // protect As/Bs until all reads done
        asm volatile("" ::: "memory");
    }

    // ---- c2 row norms -> LDS (overlay on Bs region; all Bs reads done)
    float* c2s = (float*)BsBase;
#pragma unroll
    for (int cc = 0; cc < 2; ++cc) {
        float s = c2part[cc];
        s += __shfl_xor(s, 1, 64);
        s += __shfl_xor(s, 2, 64);
        s += __shfl_xor(s, 4, 64);
        int row = (w * 2 + cc) * 8 + lrow;
        if ((lane & 7) == 0) c2s[row] = s;
    }
    __syncthreads();                 // c2s visible (loop done; drain is fine)

    // ---- epilogue: d2 = f2[m] + c2[n] - 2*S, pack f16 (octet-swizzled), store
    float c2v[4];
#pragma unroll
    for (int j = 0; j < 4; ++j)
        c2v[j] = c2s[wn * 64 + j * 16 + col];
    float fv[4][4];
#pragma unroll
    for (int i = 0; i < 4; ++i)
#pragma unroll
        for (int v = 0; v < 4; ++v)
            fv[i][v] = f2[m0 + wm * 64 + i * 16 + quad * 4 + v];

    __half* Cs = (__half*)smem;      // 128 x 128 f16 = 32 KB (overlay As[0])
#pragma unroll
    for (int h = 0; h < 2; ++h) {
        __syncthreads();             // smem free (h=0) / prev half stored (h=1)
        if ((wm >> 1) == h) {
            int mlb = (wm & 1) * 64;
#pragma unroll
            for (int i = 0; i < 4; ++i) {
#pragma unroll
                for (int j = 0; j < 4; ++j) {
#pragma unroll
                    for (int v = 0; v < 4; ++v) {
                        int ml = mlb + i * 16 + quad * 4 + v;   // 0..127
                        int nl = wn * 64 + j * 16 + col;        // 0..127
                        float d2 = fv[i][v] + c2v[j] - 2.f * acc[i][j][v];
                        int slot = (nl >> 3) ^ (ml & 7);
                        Cs[ml * 128 + slot * 8 + (nl & 7)] = __float2half(d2);
                    }
                }
            }
        }
        __syncthreads();
#pragma unroll
        for (int it = 0; it < 4; ++it) {
            int idx = it * 512 + t;  // 0..2047
            int row = idx >> 4;      // 0..127
            int o8  = idx & 15;
            int n   = n0 + o8 * 8;
            const __half* src = &Cs[row * 128 + ((o8 ^ (row & 7)) * 8)];
            __half* dst = Dm + (size_t)(m0 + h * 128 + row) * N + n;
            if (n + 7 < N) {
                *(uint4*)dst = *(const uint4*)src;
            } else if (n < N) {
                for (int e = 0; e < 8 && n + e < N; ++e) dst[e] = src[e];
            }
        }
    }
}

// ------------------------------------------------- fused per-row (1024 thr):
// Dm holds f16 d2 directly. hist -> threshold -> collect -> exact f64 top-K
// -> class scatter -> log.
__global__ __launch_bounds__(1024)
void fused_select(const __half* __restrict__ Dm,
                  const float* __restrict__ F, const float* __restrict__ C,
                  const int* __restrict__ labels, const float* __restrict__ weight,
                  float* __restrict__ out, int N)
{
    __shared__ unsigned hist[NBINS * HREP]; // 16 KB, 4 replicated copies
    __shared__ float    fs[D_DIM];
    __shared__ int      idxs[CAND_MAX];
    __shared__ double   dists[CAND_MAX];
    __shared__ float    p[NCLS];
    __shared__ float    red[1024];
    __shared__ unsigned scanbuf[256];
    __shared__ float    sT;
    __shared__ unsigned scnt;

    const int r = blockIdx.x, t = threadIdx.x;
    for (int b = t; b < NBINS * HREP; b += 1024) hist[b] = 0u;
    for (int c = t; c < NCLS; c += 1024) p[c] = 0.f;
    for (int k = t; k < D_DIM; k += 1024) fs[k] = F[(size_t)r * D_DIM + k];
    if (t == 0) { sT = 1e30f; scnt = 0u; }
    __syncthreads();

    const __half* srow = Dm + (size_t)r * N;

    // ---- pass 1: histogram, 8 elems/thread/iter (N % 8 == 0)
    for (int j = t * 8; j < N; j += 8192) {
        uint4 sv = *(const uint4*)(srow + j);
        float2 s0 = __half22float2(*(__half2*)&sv.x);
        float2 s1 = __half22float2(*(__half2*)&sv.y);
        float2 s2 = __half22float2(*(__half2*)&sv.z);
        float2 s3 = __half22float2(*(__half2*)&sv.w);
        float d2v[8] = { s0.x, s0.y, s1.x, s1.y, s2.x, s2.y, s3.x, s3.y };
#pragma unroll
        for (int e = 0; e < 8; ++e) {
            int b = (int)(d2v[e] * 0.5f);
            b = b < 0 ? 0 : (b > NBINS - 1 ? NBINS - 1 : b);
            atomicAdd(&hist[(b << 2) + (t & 3)], 1u);
        }
    }
    __syncthreads();

    // ---- threshold: blocked cumulative scan on first 256 threads
    if (t < 256) {
        unsigned loc[NBINS / 256];
        unsigned s = 0;
#pragma unroll
        for (int i = 0; i < NBINS / 256; ++i) {
            int bb = t * (NBINS / 256) + i;
            loc[i] = hist[(bb << 2) + 0] + hist[(bb << 2) + 1]
                   + hist[(bb << 2) + 2] + hist[(bb << 2) + 3];
            s += loc[i];
        }
        scanbuf[t] = s;
        __syncthreads();
        unsigned pre = 0;
        for (int u = 0; u < t; ++u) pre += scanbuf[u];
        if (pre < KSEL && pre + s >= KSEL) {
            unsigned cum = pre;
            int b = NBINS - 1;
#pragma unroll
            for (int i = 0; i < NBINS / 256; ++i) {
                cum += loc[i];
                if (cum >= KSEL) { b = t * (NBINS / 256) + i; break; }
            }
            sT = 2.0f * (float)(b + 1) + MARGIN;
        }
    } else {
        __syncthreads();
    }
    __syncthreads();
    const float Tr = sT;

    // ---- pass 2: collect candidate indices (row LLC-hot)
    for (int j = t * 8; j < N; j += 8192) {
        uint4 sv = *(const uint4*)(srow + j);
        float2 s0 = __half22float2(*(__half2*)&sv.x);
        float2 s1 = __half22float2(*(__half2*)&sv.y);
        float2 s2 = __half22float2(*(__half2*)&sv.z);
        float2 s3 = __half22float2(*(__half2*)&sv.w);
        float d2v[8] = { s0.x, s0.y, s1.x, s1.y, s2.x, s2.y, s3.x, s3.y };
#pragma unroll
        for (int e = 0; e < 8; ++e) {
            if (d2v[e] <= Tr) {
                unsigned pos = atomicAdd(&scnt, 1u);
                if (pos < CAND_MAX) idxs[pos] = j + e;
            }
        }
    }
    __syncthreads();
    int Nc = (int)scnt;
    if (Nc > CAND_MAX) Nc = CAND_MAX;

    // ---- exact f64 distances: one WAVE per candidate, coalesced C gather
    {
        const int wv = t >> 6, lane = t & 63;
        for (int i = wv; i < Nc; i += 16) {
            int ci = idxs[i];
            const float* cp = C + (size_t)ci * D_DIM;
            float4 a  = *(const float4*)(cp + lane * 8);
            float4 b  = *(const float4*)(cp + lane * 8 + 4);
            float4 fa = *(const float4*)(fs + lane * 8);
            float4 fb = *(const float4*)(fs + lane * 8 + 4);
            double d0 = (double)fa.x - (double)a.x;
            double d1 = (double)fa.y - (double)a.y;
            double d2 = (double)fa.z - (double)a.z;
            double d3 = (double)fa.w - (double)a.w;
            double d4 = (double)fb.x - (double)b.x;
            double d5 = (double)fb.y - (double)b.y;
            double d6 = (double)fb.z - (double)b.z;
            double d7 = (double)fb.w - (double)b.w;
            double acc = d0*d0 + d1*d1 + d2*d2 + d3*d3
                       + d4*d4 + d5*d5 + d6*d6 + d7*d7;
#pragma unroll
            for (int off = 32; off > 0; off >>= 1)
                acc += __shfl_down(acc, off, 64);
            if (lane == 0) dists[i] = acc;
        }
    }
    __syncthreads();

    // ---- exact rank-based top-KSEL (tie-break: lower index, lax.top_k order)
    int ksel = KSEL < Nc ? KSEL : Nc;
    for (int i = t; i < Nc; i += 1024) {
        double di = dists[i];
        int    ii = idxs[i];
        int rank = 0;
        for (int j = 0; j < Nc; ++j) {
            double dj = dists[j];
            rank += (dj < di) || (dj == di && idxs[j] < ii);
        }
        if (rank < ksel) {
            double wgt = exp(-di * GCONST) * exp((double)weight[ii]);
            atomicAdd(&p[labels[ii]], (float)wgt);
        }
    }
    __syncthreads();

    // ---- p==0 -> 1e-10, normalize, log
    float s = 0.f;
    for (int c = t; c < NCLS; c += 1024) {
        float v = p[c];
        if (v == 0.f) v = 1e-10f;
        p[c] = v;
        s += v;
    }
    red[t] = s;
    __syncthreads();
    for (int o = 512; o > 0; o >>= 1) {
        if (t < o) red[t] += red[t + o];
        __syncthreads();
    }
    float total = red[0];
    for (int c = t; c < NCLS; c += 1024)
        out[(size_t)r * NCLS + c] = logf(p[c] / total);
}

// ------------------------------------------------- launch
extern "C" void kernel_launch(void* const* d_in, const int* in_sizes, int n_in,
                              void* d_out, int out_size, void* d_ws, size_t ws_size,
                              hipStream_t stream)
{
    const float* features = (const float*)d_in[0];
    const float* centres  = (const float*)d_in[1];
    const int*   labels   = (const int*)d_in[2];
    const float* weight   = (const float*)d_in[3];
    const int B = in_sizes[0] / D_DIM;   // 512
    const int N = in_sizes[2];           // 100000
    float* out = (float*)d_out;

    uint8_t* w = (uint8_t*)d_ws;
    size_t off = 0;
    auto alloc = [&](size_t bytes) -> uint8_t* {
        uint8_t* ptr = w + off;
        off = (off + bytes + 255) & ~(size_t)255;
        return ptr;
    };
    float*          f2 = (float*)alloc((size_t)B * 4);
    unsigned short* Fb = (unsigned short*)alloc((size_t)B * D_DIM * 2);
    __half*         Dm = (__half*)alloc((size_t)B * N * 2);
    (void)ws_size;

    convertF<<<B, 256, 0, stream>>>(features, Fb, f2);

    dim3 ggrid(B / 256, (N + 127) / 128);   // m fastest
    mfma_gemm<<<ggrid, 512, 0, stream>>>(Fb, centres, f2, Dm, N);

    fused_select<<<B, 1024, 0, stream>>>(Dm, features, centres,
                                         labels, weight, out, N);
}